// Round 8
// baseline (192.285 us; speedup 1.0000x reference)
//
#include <hip/hip_runtime.h>

// WellTemparedMetaDynamics: B=32, H=200000, D=8
// eng[b]    = sum_h hgt_h[b,h] * exp(-0.5 * sum_d (cen-col)^2 * prc_h)
// new_hgt[b]= hgt * exp(-eng[b] / (kbt[b]*(gam-1)))
// outputs: cen_out (B,H+1,D) | prc_out (B,H+1,D) | hgt_out (B,H+1)  (flat concat)
//
// Ladder: R0 186 | R2 nt 213 (revert) | R3 __expf 181 | R4 align-shift neutral |
// R5 flat+shfl 187 neutral | R6 8-deep reg bursts 168.8 (MLP is THE lever).
// R7: software-pipelined double-buffer — loads of burst k+2 issued right after
// stores of burst k, so reads stay in flight during store drains. IT=32.

#define BB 32
#define HH 200000
#define DD 8
#define BLK 256
#define KB 8                      // f32x4 pairs per burst per thread
#define NH 4                      // bursts per block
#define IT (KB * NH)              // 32 float4 per thread
#define CHUNK (BLK * IT)          // 8192 float4 per block
#define F4B (HH * 2)              // 400000 float4 per batch (cen/prc)

typedef float f32x4 __attribute__((ext_vector_type(4)));

__device__ __forceinline__ void load_burst(
    const f32x4* __restrict__ cen4, const f32x4* __restrict__ prc4,
    int base, int k, int t, f32x4 (&v)[KB], f32x4 (&p)[KB])
{
    #pragma unroll
    for (int j = 0; j < KB; ++j)
        v[j] = cen4[base + (k * KB + j) * BLK + t];
    #pragma unroll
    for (int j = 0; j < KB; ++j)
        p[j] = prc4[base + (k * KB + j) * BLK + t];
}

__device__ __forceinline__ void compute_burst(
    const f32x4 (&v)[KB], const f32x4 (&p)[KB],
    const float* __restrict__ hgt_h, size_t hIn,
    int base, int k, int t, f32x4 c_my, float mask0, float& local)
{
    #pragma unroll
    for (int j = 0; j < KB; ++j) {
        const int idx = base + (k * KB + j) * BLK + t;
        const float hh = hgt_h[hIn + (idx >> 1)];   // L1-hot (warmed by hgt copy)
        const f32x4 d = v[j] - c_my;
        float s = d.x*d.x*p[j].x + d.y*d.y*p[j].y
                + d.z*d.z*p[j].z + d.w*d.w*p[j].w;
        s += __shfl_xor(s, 1);                      // pair-combine halves
        local += mask0 * hh * __expf(-0.5f * s);
    }
}

__device__ __forceinline__ void store_burst(
    f32x4* __restrict__ co, f32x4* __restrict__ po,
    int base, int k, int t, const f32x4 (&v)[KB], const f32x4 (&p)[KB])
{
    #pragma unroll
    for (int j = 0; j < KB; ++j)
        co[base + (k * KB + j) * BLK + t] = v[j];
    #pragma unroll
    for (int j = 0; j < KB; ++j)
        po[base + (k * KB + j) * BLK + t] = p[j];
}

__global__ __launch_bounds__(BLK) void wtmtd_main(
    const float* __restrict__ col,
    const float* __restrict__ cen,
    const float* __restrict__ prc_h,
    const float* __restrict__ hgt_h,
    float* __restrict__ cen_out,
    float* __restrict__ prc_out,
    float* __restrict__ hgt_out,
    float* __restrict__ partials)
{
    const int b = blockIdx.y;
    const int t = threadIdx.x;

    const size_t hIn  = (size_t)b * HH;
    const size_t hOut = (size_t)b * (HH + 1);

    const f32x4* cen4 = (const f32x4*)cen   + (size_t)b * F4B;
    const f32x4* prc4 = (const f32x4*)prc_h + (size_t)b * F4B;
    f32x4* co = (f32x4*)cen_out + (size_t)b * (F4B + 2);
    f32x4* po = (f32x4*)prc_out + (size_t)b * (F4B + 2);

    const f32x4* colv = (const f32x4*)(col + (size_t)b * DD);
    const f32x4 c_my  = colv[t & 1];
    const float mask0 = (t & 1) ? 0.0f : 1.0f;

    const int base  = blockIdx.x * CHUNK;   // float4 index within batch
    const int hbase = base >> 1;            // hill index within batch

    // hgt copy: fully coalesced scalar (256B/wave-instr); warms L1 for re-reads.
    #pragma unroll
    for (int i = 0; i < IT / 2; ++i) {      // 16 * 256 = 4096 hills per block
        const int h = hbase + i * BLK + t;
        if (h < HH) hgt_out[hOut + h] = hgt_h[hIn + h];
    }

    float local = 0.0f;
    const bool full = (base + CHUNK) <= F4B;   // block-uniform

    if (full) {
        f32x4 vA[KB], pA[KB], vB[KB], pB[KB];
        // prologue: 32 loads in flight
        load_burst(cen4, prc4, base, 0, t, vA, pA);
        load_burst(cen4, prc4, base, 1, t, vB, pB);

        // k=0: compute/store A, refill A with burst 2
        compute_burst(vA, pA, hgt_h, hIn, base, 0, t, c_my, mask0, local);
        store_burst(co, po, base, 0, t, vA, pA);
        load_burst(cen4, prc4, base, 2, t, vA, pA);

        // k=1: compute/store B, refill B with burst 3
        compute_burst(vB, pB, hgt_h, hIn, base, 1, t, c_my, mask0, local);
        store_burst(co, po, base, 1, t, vB, pB);
        load_burst(cen4, prc4, base, 3, t, vB, pB);

        // k=2, k=3: drain
        compute_burst(vA, pA, hgt_h, hIn, base, 2, t, c_my, mask0, local);
        store_burst(co, po, base, 2, t, vA, pA);
        compute_burst(vB, pB, hgt_h, hIn, base, 3, t, c_my, mask0, local);
        store_burst(co, po, base, 3, t, vB, pB);
    } else {
        #pragma unroll 4
        for (int i = 0; i < IT; ++i) {
            const int idx = base + i * BLK + t;
            if (idx < F4B) {                 // pairs stay together (F4B even)
                const f32x4 v = cen4[idx];
                const f32x4 p = prc4[idx];
                const float hh = hgt_h[hIn + (idx >> 1)];

                const f32x4 d = v - c_my;
                float s = d.x*d.x*p.x + d.y*d.y*p.y + d.z*d.z*p.z + d.w*d.w*p.w;
                s += __shfl_xor(s, 1);
                local += mask0 * hh * __expf(-0.5f * s);

                co[idx] = v;
                po[idx] = p;
            }
        }
    }

    // wave64 shuffle reduce, then cross-wave via LDS
    #pragma unroll
    for (int off = 32; off > 0; off >>= 1)
        local += __shfl_down(local, off);

    __shared__ float sred[BLK / 64];
    const int lane = t & 63;
    const int wv   = t >> 6;
    if (lane == 0) sred[wv] = local;
    __syncthreads();
    if (t == 0) {
        float s = 0.0f;
        #pragma unroll
        for (int i = 0; i < BLK / 64; ++i) s += sred[i];
        partials[(size_t)b * gridDim.x + blockIdx.x] = s;
    }
}

// Final: reduce partials (fixed order -> deterministic), compute new hill,
// write the appended slot H for all three outputs.
__global__ __launch_bounds__(64) void wtmtd_fin(
    const float* __restrict__ partials, int nblk,
    const float* __restrict__ col,
    const float* __restrict__ kbt,
    const float* __restrict__ prc,
    const float* __restrict__ hgt,
    const float* __restrict__ gam,
    float* __restrict__ cen_out,
    float* __restrict__ prc_out,
    float* __restrict__ hgt_out)
{
    const int b = blockIdx.x;

    float s = 0.0f;
    for (int i = threadIdx.x; i < nblk; i += 64)
        s += partials[(size_t)b * nblk + i];
    #pragma unroll
    for (int off = 32; off > 0; off >>= 1)
        s += __shfl_down(s, off);
    s = __shfl(s, 0);   // broadcast eng[b]

    const float det = kbt[b] * (gam[0] - 1.0f);
    const float new_hgt = hgt[0] * expf(-s / det);

    const size_t outBase = (size_t)b * (HH + 1);
    if (threadIdx.x < DD) {
        cen_out[(outBase + HH) * DD + threadIdx.x] = col[(size_t)b * DD + threadIdx.x];
        prc_out[(outBase + HH) * DD + threadIdx.x] = prc[threadIdx.x];
    }
    if (threadIdx.x == 0)
        hgt_out[outBase + HH] = new_hgt;
}

extern "C" void kernel_launch(void* const* d_in, const int* in_sizes, int n_in,
                              void* d_out, int out_size, void* d_ws, size_t ws_size,
                              hipStream_t stream) {
    const float* col   = (const float*)d_in[0];
    const float* cen   = (const float*)d_in[1];
    const float* prc_h = (const float*)d_in[2];
    const float* hgt_h = (const float*)d_in[3];
    const float* kbt   = (const float*)d_in[4];
    const float* prc   = (const float*)d_in[5];
    const float* hgt   = (const float*)d_in[6];
    const float* gam   = (const float*)d_in[7];

    float* cen_out = (float*)d_out;
    float* prc_out = cen_out + (size_t)BB * (HH + 1) * DD;
    float* hgt_out = prc_out + (size_t)BB * (HH + 1) * DD;

    float* partials = (float*)d_ws;

    const int nblkx = (F4B + CHUNK - 1) / CHUNK;  // 49
    dim3 grid(nblkx, BB);

    wtmtd_main<<<grid, BLK, 0, stream>>>(col, cen, prc_h, hgt_h,
                                         cen_out, prc_out, hgt_out, partials);
    wtmtd_fin<<<BB, 64, 0, stream>>>(partials, nblkx, col, kbt, prc, hgt, gam,
                                     cen_out, prc_out, hgt_out);
}

// Round 9
// 169.621 us; speedup vs baseline: 1.1336x; 1.1336x over previous
//
#include <hip/hip_runtime.h>

// WellTemparedMetaDynamics: B=32, H=200000, D=8
// eng[b]    = sum_h hgt_h[b,h] * exp(-0.5 * sum_d (cen-col)^2 * prc_h)
// new_hgt[b]= hgt * exp(-eng[b] / (kbt[b]*(gam-1)))
// outputs: cen_out (B,H+1,D) | prc_out (B,H+1,D) | hgt_out (B,H+1)  (flat concat)
//
// Ladder: R0 186 | R2 nt 213 (revert) | R3 __expf 181 | R4 align-shift neutral |
// R5 flat+shfl 187 neutral | R6 8-deep reg bursts 168.8 | R7 explicit SW pipeline
// 192 (REGRESSED — extra liveness/occupancy loss; revert). R8: R6 structure with
// burst depth 16 (one 32-load mega-burst, then 32-store burst). Single variable.

#define BB 32
#define HH 200000
#define DD 8
#define BLK 256
#define KB 16                     // f32x4 pairs per burst per thread (was 8)
#define IT 16                     // float4 per thread (unchanged)
#define CHUNK (BLK * IT)          // 4096 float4 per block
#define F4B (HH * 2)              // 400000 float4 per batch (cen/prc)

typedef float f32x4 __attribute__((ext_vector_type(4)));

__global__ __launch_bounds__(BLK) void wtmtd_main(
    const float* __restrict__ col,
    const float* __restrict__ cen,
    const float* __restrict__ prc_h,
    const float* __restrict__ hgt_h,
    float* __restrict__ cen_out,
    float* __restrict__ prc_out,
    float* __restrict__ hgt_out,
    float* __restrict__ partials)
{
    const int b = blockIdx.y;
    const int t = threadIdx.x;

    const size_t hIn  = (size_t)b * HH;
    const size_t hOut = (size_t)b * (HH + 1);

    const f32x4* cen4 = (const f32x4*)cen   + (size_t)b * F4B;
    const f32x4* prc4 = (const f32x4*)prc_h + (size_t)b * F4B;
    f32x4* co = (f32x4*)cen_out + (size_t)b * (F4B + 2);
    f32x4* po = (f32x4*)prc_out + (size_t)b * (F4B + 2);

    // lane-constant: col half matching this lane's parity, and even-lane mask
    const f32x4* colv = (const f32x4*)(col + (size_t)b * DD);
    const f32x4 c_my  = colv[t & 1];
    const float mask0 = (t & 1) ? 0.0f : 1.0f;

    const int base  = blockIdx.x * CHUNK;   // float4 index within batch
    const int hbase = base >> 1;            // hill index within batch

    // hgt copy: fully coalesced scalar (256B/wave-instr); warms L1 for re-reads.
    #pragma unroll
    for (int i = 0; i < IT / 2; ++i) {      // 8 * 256 = 2048 hills per block
        const int h = hbase + i * BLK + t;
        if (h < HH) hgt_out[hOut + h] = hgt_h[hIn + h];
    }

    float local = 0.0f;
    const bool full = (base + CHUNK) <= F4B;   // block-uniform

    if (full) {
        f32x4 v[KB], p[KB];
        // ---- 32 independent loads in flight (32KB/wave read burst)
        #pragma unroll
        for (int j = 0; j < KB; ++j)
            v[j] = cen4[base + j * BLK + t];
        #pragma unroll
        for (int j = 0; j < KB; ++j)
            p[j] = prc4[base + j * BLK + t];

        // ---- energy for all 16 pairs
        #pragma unroll
        for (int j = 0; j < KB; ++j) {
            const int idx = base + j * BLK + t;
            const float hh = hgt_h[hIn + (idx >> 1)];   // L1-hot
            const f32x4 d = v[j] - c_my;
            float s = d.x*d.x*p[j].x + d.y*d.y*p[j].y
                    + d.z*d.z*p[j].z + d.w*d.w*p[j].w;
            s += __shfl_xor(s, 1);                      // pair-combine halves
            local += mask0 * hh * __expf(-0.5f * s);
        }

        // ---- 32-deep store burst (32KB/wave write burst)
        #pragma unroll
        for (int j = 0; j < KB; ++j)
            co[base + j * BLK + t] = v[j];
        #pragma unroll
        for (int j = 0; j < KB; ++j)
            po[base + j * BLK + t] = p[j];
    } else {
        #pragma unroll 4
        for (int i = 0; i < IT; ++i) {
            const int idx = base + i * BLK + t;
            if (idx < F4B) {                 // pairs stay together (F4B even)
                const f32x4 v = cen4[idx];
                const f32x4 p = prc4[idx];
                const float hh = hgt_h[hIn + (idx >> 1)];

                const f32x4 d = v - c_my;
                float s = d.x*d.x*p.x + d.y*d.y*p.y + d.z*d.z*p.z + d.w*d.w*p.w;
                s += __shfl_xor(s, 1);
                local += mask0 * hh * __expf(-0.5f * s);

                co[idx] = v;
                po[idx] = p;
            }
        }
    }

    // wave64 shuffle reduce, then cross-wave via LDS
    #pragma unroll
    for (int off = 32; off > 0; off >>= 1)
        local += __shfl_down(local, off);

    __shared__ float sred[BLK / 64];
    const int lane = t & 63;
    const int wv   = t >> 6;
    if (lane == 0) sred[wv] = local;
    __syncthreads();
    if (t == 0) {
        float s = 0.0f;
        #pragma unroll
        for (int i = 0; i < BLK / 64; ++i) s += sred[i];
        partials[(size_t)b * gridDim.x + blockIdx.x] = s;
    }
}

// Final: reduce partials (fixed order -> deterministic), compute new hill,
// write the appended slot H for all three outputs.
__global__ __launch_bounds__(64) void wtmtd_fin(
    const float* __restrict__ partials, int nblk,
    const float* __restrict__ col,
    const float* __restrict__ kbt,
    const float* __restrict__ prc,
    const float* __restrict__ hgt,
    const float* __restrict__ gam,
    float* __restrict__ cen_out,
    float* __restrict__ prc_out,
    float* __restrict__ hgt_out)
{
    const int b = blockIdx.x;

    float s = 0.0f;
    for (int i = threadIdx.x; i < nblk; i += 64)
        s += partials[(size_t)b * nblk + i];
    #pragma unroll
    for (int off = 32; off > 0; off >>= 1)
        s += __shfl_down(s, off);
    s = __shfl(s, 0);   // broadcast eng[b]

    const float det = kbt[b] * (gam[0] - 1.0f);
    const float new_hgt = hgt[0] * expf(-s / det);

    const size_t outBase = (size_t)b * (HH + 1);
    if (threadIdx.x < DD) {
        cen_out[(outBase + HH) * DD + threadIdx.x] = col[(size_t)b * DD + threadIdx.x];
        prc_out[(outBase + HH) * DD + threadIdx.x] = prc[threadIdx.x];
    }
    if (threadIdx.x == 0)
        hgt_out[outBase + HH] = new_hgt;
}

extern "C" void kernel_launch(void* const* d_in, const int* in_sizes, int n_in,
                              void* d_out, int out_size, void* d_ws, size_t ws_size,
                              hipStream_t stream) {
    const float* col   = (const float*)d_in[0];
    const float* cen   = (const float*)d_in[1];
    const float* prc_h = (const float*)d_in[2];
    const float* hgt_h = (const float*)d_in[3];
    const float* kbt   = (const float*)d_in[4];
    const float* prc   = (const float*)d_in[5];
    const float* hgt   = (const float*)d_in[6];
    const float* gam   = (const float*)d_in[7];

    float* cen_out = (float*)d_out;
    float* prc_out = cen_out + (size_t)BB * (HH + 1) * DD;
    float* hgt_out = prc_out + (size_t)BB * (HH + 1) * DD;

    float* partials = (float*)d_ws;

    const int nblkx = (F4B + CHUNK - 1) / CHUNK;  // 98
    dim3 grid(nblkx, BB);

    wtmtd_main<<<grid, BLK, 0, stream>>>(col, cen, prc_h, hgt_h,
                                         cen_out, prc_out, hgt_out, partials);
    wtmtd_fin<<<BB, 64, 0, stream>>>(partials, nblkx, col, kbt, prc, hgt, gam,
                                     cen_out, prc_out, hgt_out);
}